// Round 4
// baseline (609.777 us; speedup 1.0000x reference)
//
#include <hip/hip_runtime.h>

// LogicGatedSNN: fused kernel, wave-per-row, x as LDS bitmask.
//   IN_FEATURES = OUT_FEATURES = 8192, THRESHOLD = 50.0
//
// v4: v3 was throughput-bound on the CU-side vector-memory path:
// 1072 MB/dispatch CU-side (syn + trace + writes + 268 MB of x re-reads
// from L2) at 5.4 TB/s = 87% of the float4-copy ceiling (25.6 B/cy/CU).
// Occupancy/MLP changes (v1/v2/v3) never moved throughput -> the x
// re-read stream is the only removable traffic.
//   - x (8192 floats, all exactly 0.0/1.0) is packed ONCE per block into
//     a 1 KB LDS bitmask via __ballot (32 KB L2 read/block, ~3 us).
//   - Both phases read 1 dword per 8 lanes (broadcast, conflict-free)
//     and bit-test; phase-1 sum becomes an exact integer popcount-style
//     accumulation. x vector traffic: 268 MB -> ~0.
//   - Single __syncthreads after pack; phases remain barrier-free,
//     wave-per-row, butterfly reduce, nontemporal trace stores.

#define IN_F 8192
#define OUT_F 8192
#define SYN_THRESH 50.0f

typedef float vfloat4 __attribute__((ext_vector_type(4)));

__global__ __launch_bounds__(256, 8) void snn_fused_wave(
    const float* __restrict__ x,      // [IN_F] spike_input (0/1)
    const float* __restrict__ syn,    // [OUT_F, IN_F] synapse_states
    const float* __restrict__ mp,     // [OUT_F] membrane_potential
    const float* __restrict__ thr,    // [OUT_F] adaptive_threshold
    const float* __restrict__ trace,  // [OUT_F, IN_F] eligibility_trace
    float* __restrict__ out_spikes,   // [OUT_F]
    float* __restrict__ out_vnew,     // [OUT_F]
    float* __restrict__ out_trace)    // [OUT_F, IN_F]
{
    __shared__ unsigned int xmask[256];          // 8192 bits = 1 KB

    const int wave = threadIdx.x >> 6;
    const int lane = threadIdx.x & 63;
    const int row  = (blockIdx.x << 2) | wave;   // 4 rows per block
    const long long base = (long long)row * IN_F;

    // ---- pack x -> bitmask (each wave covers 2048 elements, 32 ballots)
    // bit j of xmask[d] == (x[d*32 + j%32 ...]); precisely:
    // element e = w*2048 + i*64 + lane  ->  dword e>>5 = w*64+i*2 (+lane>>5)
#pragma unroll 4
    for (int i = 0; i < 32; ++i) {
        const float v = x[(wave << 11) + (i << 6) + lane];
        const unsigned long long m = __ballot(v > 0.5f);
        if (lane == 0) {
            xmask[(wave << 6) + (i << 1)]     = (unsigned)m;
            xmask[(wave << 6) + (i << 1) + 1] = (unsigned)(m >> 32);
        }
    }
    __syncthreads();

    const vfloat4* __restrict__ syn4 = (const vfloat4*)(syn + base);
    const vfloat4* __restrict__ tr4  = (const vfloat4*)(trace + base);
    vfloat4* __restrict__ ot4        = (vfloat4*)(out_trace + base);

    // ---- phase 1: current = popcount( (syn>50) & x )
    // float4 index idx -> element base e0 = idx*4; dword = idx>>3,
    // nibble shift = (lane&7)*4.
    int cnt = 0;
#pragma unroll 1
    for (int c = 0; c < 8; ++c) {
        vfloat4 s[4]; unsigned nib[4];
#pragma unroll
        for (int u = 0; u < 4; ++u) {
            const int idx = ((((c << 2) + u) << 6) | lane);
            s[u] = syn4[idx];
            const unsigned dw = xmask[idx >> 3];         // 8-lane broadcast
            nib[u] = (dw >> ((lane & 7) << 2)) & 0xFu;
        }
#pragma unroll
        for (int u = 0; u < 4; ++u) {
            cnt += (s[u].x > SYN_THRESH) & (int)(nib[u] & 1u);
            cnt += (s[u].y > SYN_THRESH) & (int)((nib[u] >> 1) & 1u);
            cnt += (s[u].z > SYN_THRESH) & (int)((nib[u] >> 2) & 1u);
            cnt += (s[u].w > SYN_THRESH) & (int)((nib[u] >> 3) & 1u);
        }
    }
    float sum = (float)cnt;

    // in-register butterfly: all 64 lanes end with the full row sum
#pragma unroll
    for (int off = 32; off > 0; off >>= 1)
        sum += __shfl_xor(sum, off, 64);

    // ---- phase 2: LIF update (wave-uniform; every lane computes it)
    const float v     = mp[row] * 0.6f + sum;
    const float spike = (v >= thr[row]) ? 1.0f : 0.0f;
    if (lane == 0) {
        out_spikes[row] = spike;
        out_vnew[row]   = v * (1.0f - spike) * 0.3f;
    }
    // fold spike into the bit test: addend = spike && x[i]
    const unsigned smask = (spike > 0.0f) ? 0xFu : 0x0u;

    // ---- phase 3: trace_new = clip(trace*0.7 + spike*x, 0, 3)
#pragma unroll 1
    for (int c = 0; c < 8; ++c) {
        vfloat4 t[4]; unsigned nib[4];
#pragma unroll
        for (int u = 0; u < 4; ++u) {
            const int idx = ((((c << 2) + u) << 6) | lane);
            t[u] = tr4[idx];
            const unsigned dw = xmask[idx >> 3];
            nib[u] = ((dw >> ((lane & 7) << 2)) & 0xFu) & smask;
        }
#pragma unroll
        for (int u = 0; u < 4; ++u) {
            const int idx = ((((c << 2) + u) << 6) | lane);
            vfloat4 o;
            o.x = fminf(fmaxf(fmaf(t[u].x, 0.7f, (nib[u] & 1u) ? 1.0f : 0.0f), 0.0f), 3.0f);
            o.y = fminf(fmaxf(fmaf(t[u].y, 0.7f, (nib[u] & 2u) ? 1.0f : 0.0f), 0.0f), 3.0f);
            o.z = fminf(fmaxf(fmaf(t[u].z, 0.7f, (nib[u] & 4u) ? 1.0f : 0.0f), 0.0f), 3.0f);
            o.w = fminf(fmaxf(fmaf(t[u].w, 0.7f, (nib[u] & 8u) ? 1.0f : 0.0f), 0.0f), 3.0f);
            __builtin_nontemporal_store(o, &ot4[idx]);
        }
    }
}

extern "C" void kernel_launch(void* const* d_in, const int* in_sizes, int n_in,
                              void* d_out, int out_size, void* d_ws, size_t ws_size,
                              hipStream_t stream) {
    const float* x     = (const float*)d_in[0];  // spike_input        [1, 8192]
    const float* syn   = (const float*)d_in[1];  // synapse_states     [8192, 8192]
    const float* mp    = (const float*)d_in[2];  // membrane_potential [8192]
    const float* thr   = (const float*)d_in[3];  // adaptive_threshold [8192]
    const float* trace = (const float*)d_in[4];  // eligibility_trace  [8192, 8192]

    float* out = (float*)d_out;
    float* out_spikes = out;                     // [8192]
    float* out_vnew   = out + OUT_F;             // [8192]
    float* out_trace  = out + 2 * OUT_F;         // [8192, 8192]

    snn_fused_wave<<<OUT_F / 4, 256, 0, stream>>>(
        x, syn, mp, thr, trace, out_spikes, out_vnew, out_trace);
}

// Round 6
// 585.270 us; speedup vs baseline: 1.0419x; 1.0419x over previous
//
#include <hip/hip_runtime.h>

// LogicGatedSNN v5.1: DE-FUSED into two pure streaming kernels.
// (v5 with K2 row/column indexing fixed: a row is 2048 float4, so
//  row = idx>>11 and x-column = idx&2047; v5 used >>9 / &511.)
//
// Evidence from v1-v4: every fused variant pins at 187-220 us / <2.9 TB/s
// across occupancy 20-70%, VGPR 24-92, logical traffic 805-1341 MB.
// The fused structure (reduction stream + dependent RMW stream,
// phase-coupled per row) is the invariant -> de-fuse.
//
//  K1 snn_matvec: current[row] = sum x[i]*(syn>50); LIF update.
//     Pure read stream (268 MB). syn loaded NONTEMPORAL (one-pass data,
//     keep the Infinity Cache for trace). x is L1-resident (32 KB).
//  K2 snn_trace: out_trace = clip(trace*0.7 + spike[row]*x[col], 0, 3).
//     Structurally the 6.29 TB/s float4-copy microbench: coalesced read
//     + coalesced write, no cross-lane, no barriers; spike[row] is
//     wave-uniform, x is L1-hot.
//
// Ordering: same stream -> K2 sees K1's spikes.

#define IN_F 8192
#define OUT_F 8192
#define SYN_THRESH 50.0f

typedef float vfloat4 __attribute__((ext_vector_type(4)));

// ---------------- K1: matvec + LIF (wave-per-row) ----------------
__global__ __launch_bounds__(256, 8) void snn_matvec(
    const float* __restrict__ x,      // [IN_F] spike_input (0/1)
    const float* __restrict__ syn,    // [OUT_F, IN_F]
    const float* __restrict__ mp,     // [OUT_F]
    const float* __restrict__ thr,    // [OUT_F]
    float* __restrict__ out_spikes,   // [OUT_F]
    float* __restrict__ out_vnew)     // [OUT_F]
{
    const int wave = threadIdx.x >> 6;
    const int lane = threadIdx.x & 63;
    const int row  = (blockIdx.x << 2) | wave;   // 4 rows per block
    const long long base = (long long)row * IN_F;

    const vfloat4* __restrict__ syn4 = (const vfloat4*)(syn + base);
    const vfloat4* __restrict__ x4   = (const vfloat4*)x;

    // 2048 float4 per row / 64 lanes = 32 per lane, in 8 chunks of 4
    // (bounded unroll keeps VGPR < 64 -> 8 waves/SIMD).
    float sum = 0.0f;
#pragma unroll 1
    for (int c = 0; c < 8; ++c) {
        vfloat4 s[4], xx[4];
#pragma unroll
        for (int u = 0; u < 4; ++u) {
            const int idx = (((c << 2) + u) << 6) | lane;   // coalesced
            s[u]  = __builtin_nontemporal_load(&syn4[idx]); // one-pass stream
            xx[u] = x4[idx];                                // L1-resident
        }
#pragma unroll
        for (int u = 0; u < 4; ++u) {
            sum += ((s[u].x > SYN_THRESH) ? xx[u].x : 0.0f)
                 + ((s[u].y > SYN_THRESH) ? xx[u].y : 0.0f)
                 + ((s[u].z > SYN_THRESH) ? xx[u].z : 0.0f)
                 + ((s[u].w > SYN_THRESH) ? xx[u].w : 0.0f);
        }
    }

    // butterfly: all 64 lanes end with the row sum
#pragma unroll
    for (int off = 32; off > 0; off >>= 1)
        sum += __shfl_xor(sum, off, 64);

    if (lane == 0) {
        const float v     = mp[row] * 0.6f + sum;
        const float spike = (v >= thr[row]) ? 1.0f : 0.0f;
        out_spikes[row] = spike;
        out_vnew[row]   = v * (1.0f - spike) * 0.3f;
    }
}

// ---------------- K2: trace update (pure stream) ----------------
// Each block owns 4 contiguous rows = 8192 float4 (128 KB region).
// Row stride = 2048 float4: row-in-block = idx>>11, col = idx&2047.
__global__ __launch_bounds__(256, 8) void snn_trace(
    const float* __restrict__ x,        // [IN_F]
    const float* __restrict__ trace,    // [OUT_F, IN_F]
    const float* __restrict__ spikes,   // [OUT_F]  (from K1)
    float* __restrict__ out_trace)      // [OUT_F, IN_F]
{
    const long long blk4 = (long long)blockIdx.x * 8192;   // float4 units
    const vfloat4* __restrict__ tr4 = (const vfloat4*)trace + blk4;
    vfloat4* __restrict__ ot4       = (vfloat4*)out_trace + blk4;
    const vfloat4* __restrict__ x4  = (const vfloat4*)x;   // 2048 float4
    const int row0 = blockIdx.x << 2;
    const int tid  = threadIdx.x;

#pragma unroll 1
    for (int c = 0; c < 8; ++c) {
        vfloat4 t[4], xx[4];
        float sp[4];
#pragma unroll
        for (int u = 0; u < 4; ++u) {
            const int idx = (c << 10) | (u << 8) | tid;     // 0..8191, coalesced
            t[u]  = tr4[idx];
            xx[u] = x4[idx & 2047];                         // col within row
            sp[u] = spikes[row0 + (idx >> 11)];             // row within block
        }
#pragma unroll
        for (int u = 0; u < 4; ++u) {
            const int idx = (c << 10) | (u << 8) | tid;
            vfloat4 o;
            o.x = fminf(fmaxf(fmaf(t[u].x, 0.7f, sp[u] * xx[u].x), 0.0f), 3.0f);
            o.y = fminf(fmaxf(fmaf(t[u].y, 0.7f, sp[u] * xx[u].y), 0.0f), 3.0f);
            o.z = fminf(fmaxf(fmaf(t[u].z, 0.7f, sp[u] * xx[u].z), 0.0f), 3.0f);
            o.w = fminf(fmaxf(fmaf(t[u].w, 0.7f, sp[u] * xx[u].w), 0.0f), 3.0f);
            ot4[idx] = o;                                   // regular store (m13 pattern)
        }
    }
}

extern "C" void kernel_launch(void* const* d_in, const int* in_sizes, int n_in,
                              void* d_out, int out_size, void* d_ws, size_t ws_size,
                              hipStream_t stream) {
    const float* x     = (const float*)d_in[0];  // spike_input        [1, 8192]
    const float* syn   = (const float*)d_in[1];  // synapse_states     [8192, 8192]
    const float* mp    = (const float*)d_in[2];  // membrane_potential [8192]
    const float* thr   = (const float*)d_in[3];  // adaptive_threshold [8192]
    const float* trace = (const float*)d_in[4];  // eligibility_trace  [8192, 8192]

    float* out = (float*)d_out;
    float* out_spikes = out;                     // [8192]
    float* out_vnew   = out + OUT_F;             // [8192]
    float* out_trace  = out + 2 * OUT_F;         // [8192, 8192]

    snn_matvec<<<OUT_F / 4, 256, 0, stream>>>(
        x, syn, mp, thr, out_spikes, out_vnew);
    snn_trace<<<OUT_F / 4, 256, 0, stream>>>(
        x, trace, out_spikes, out_trace);
}